// Round 2
// baseline (2065.739 us; speedup 1.0000x reference)
//
#include <hip/hip_runtime.h>
#include <math.h>

// Problem constants: B=256, T=512, D=128, H=128 (3H=384), U=64, A=10, LAMDA=0.5
#define B_ 256
#define T_ 512
#define D_ 128
#define H_ 128
#define NG 1308160   // 511*256*10 gumbels per agent

// ---------------- threefry2x32 (exact JAX semantics) ----------------
__device__ __forceinline__ void tf2x32(unsigned k0, unsigned k1, unsigned x0, unsigned x1,
                                       unsigned& o0, unsigned& o1) {
  unsigned k2 = k0 ^ k1 ^ 0x1BD11BDAu;
  unsigned v0 = x0 + k0, v1 = x1 + k1;
#define TFR(r) { v0 += v1; v1 = (v1 << (r)) | (v1 >> (32 - (r))); v1 ^= v0; }
  TFR(13) TFR(15) TFR(26) TFR(6)   v0 += k1; v1 += k2 + 1u;
  TFR(17) TFR(29) TFR(16) TFR(24)  v0 += k2; v1 += k0 + 2u;
  TFR(13) TFR(15) TFR(26) TFR(6)   v0 += k0; v1 += k1 + 3u;
  TFR(17) TFR(29) TFR(16) TFR(24)  v0 += k1; v1 += k2 + 4u;
  TFR(13) TFR(15) TFR(26) TFR(6)   v0 += k2; v1 += k0 + 5u;
#undef TFR
  o0 = v0; o1 = v1;
}

// bits -> gumbel, replicating jax uniform(minval=tiny,maxval=1) + -log(-log(u))
__device__ __forceinline__ float gumbel_f(unsigned bits) {
  const float tiny = 1.17549435e-38f;
  float u = __uint_as_float((bits >> 9) | 0x3f800000u) - 1.0f;
  // (1.0f - tiny) == 1.0f in fp32, so *(maxval-minval)+minval == u + tiny
  u = u + tiny;
  u = fmaxf(tiny, u);
  return -logf(-logf(u));
}

// ---------------- P0: split keys table (jax_threefry_partitionable=True) ----------------
// foldlike split: key_i = (o0, o1) = threefry2x32((0,42), (hi=0, lo=i))
__global__ void p0_keys(unsigned* __restrict__ keys_tab) {
  int i = blockIdx.x * blockDim.x + threadIdx.x;
  if (i >= 1024) return;
  unsigned o0, o1;
  tf2x32(0u, 42u, 0u, (unsigned)i, o0, o1);
  keys_tab[2 * i] = o0; keys_tab[2 * i + 1] = o1;
}

// ---------------- P3: gumbel tables for both agents ----------------
// partitionable random_bits(key,32,(256,10)): flat f = b*10+a ->
//   (b1,b2) = threefry2x32(key, (0, f)); bits = b1 ^ b2
__global__ void p3_gumbel(const unsigned* __restrict__ keys_tab,
                          float* __restrict__ g1, float* __restrict__ g2) {
  int gid = blockIdx.x * blockDim.x + threadIdx.x;
  if (gid >= 2 * NG) return;
  int agent = gid / NG;
  int rem = gid - agent * NG;
  int tm1 = rem / 2560;
  int f = rem - tm1 * 2560;
  int t = tm1 + 1;
  int ki = 2 * t + agent;
  unsigned k0 = keys_tab[2 * ki], k1 = keys_tab[2 * ki + 1];
  unsigned b1, b2;
  tf2x32(k0, k1, 0u, (unsigned)f, b1, b2);
  float g = gumbel_f(b1 ^ b2);
  (agent ? g2 : g1)[rem] = g;
}

// ---------------- P2: agent-2 actions (depend only on x) ----------------
// a2[t][b] = argmax_a( (tanh(x[b,t]@w1.T + b1) @ w2.T + b2)[a] + g2[t,b,a] )
__global__ __launch_bounds__(256) void p2_a2(const float* __restrict__ x,
    const float* __restrict__ w1, const float* __restrict__ b1,
    const float* __restrict__ w2, const float* __restrict__ b2,
    const float* __restrict__ g2_tab, int* __restrict__ a2_tab) {
  __shared__ float4 w1v[32][64];                 // w1v[c][m] = w1[m][4c..4c+3]
  __shared__ __align__(16) float w2s[10][64];
  __shared__ float b1s[64];
  __shared__ float b2s[10];
  __shared__ __align__(16) float zs[4][8][64];
  int tid = threadIdx.x, wv = tid >> 6, lane = tid & 63;
  for (int idx = tid; idx < 2048; idx += 256) {
    int c = idx >> 6, m = idx & 63;
    w1v[c][m] = ((const float4*)(w1 + m * 128))[c];
  }
  for (int idx = tid; idx < 640; idx += 256) w2s[idx >> 6][idx & 63] = w2[idx];
  if (tid < 64) b1s[tid] = b1[tid];
  if (tid < 10) b2s[tid] = b2[tid];
  __syncthreads();
  int s0 = blockIdx.x * 32 + wv * 8;
  int t = (s0 >> 8) + 1;
  int m = lane;
  // phase 1: hidden layer z for 8 samples (pairs share the w1 reads)
  for (int pr = 0; pr < 4; pr++) {
    int sA = s0 + 2 * pr, sB = sA + 1;
    int bA = sA & 255, bB = sB & 255;
    const float4* xA = (const float4*)(x + ((size_t)bA * T_ + t) * D_);
    const float4* xB = (const float4*)(x + ((size_t)bB * T_ + t) * D_);
    float accA = 0.f, accB = 0.f;
    #pragma unroll
    for (int c = 0; c < 32; c++) {
      float4 w4 = w1v[c][m];
      float4 xa = xA[c], xb = xB[c];
      accA += w4.x * xa.x + w4.y * xa.y + w4.z * xa.z + w4.w * xa.w;
      accB += w4.x * xb.x + w4.y * xb.y + w4.z * xb.z + w4.w * xb.w;
    }
    zs[wv][2 * pr][m]     = tanhf(accA + b1s[m]);
    zs[wv][2 * pr + 1][m] = tanhf(accB + b1s[m]);
  }
  __syncthreads();
  // phase 2: logits + gumbel + argmax
  int a = lane & 15, kc = lane >> 4;
  for (int i = 0; i < 8; i++) {
    int s = s0 + i, b = s & 255;
    float p = 0.f;
    if (a < 10) {
      const float4* zp = (const float4*)(&zs[wv][i][16 * kc]);
      const float4* wp = (const float4*)(&w2s[a][16 * kc]);
      #pragma unroll
      for (int c = 0; c < 4; c++) {
        float4 zv = zp[c], w4 = wp[c];
        p += w4.x * zv.x + w4.y * zv.y + w4.z * zv.z + w4.w * zv.w;
      }
    }
    p += __shfl_xor(p, 16);
    p += __shfl_xor(p, 32);
    float val = -3.0e38f;
    if (a < 10) {
      float g = g2_tab[((size_t)(t - 1) * 256 + b) * 10 + a];
      val = (p + b2s[a]) + g;
    }
    float best = 0.f; int bi = 0;
    #pragma unroll
    for (int aa = 0; aa < 10; aa++) {
      float v = __shfl(val, aa);      // lanes 0..9 have kc=0, a=lane
      if (aa == 0 || v > best) { best = v; bi = aa; }
    }
    if (lane == 0) a2_tab[(size_t)(t - 1) * 256 + b] = bi;
  }
}

// ---------------- S: sequential per-batch kernel (1 block = 1 batch elem) ----------------
__global__ __launch_bounds__(512, 2) void seq_kernel(
    const float* __restrict__ x, const int* __restrict__ mask,
    const float* __restrict__ w_ih, const float* __restrict__ w_hh,
    const float* __restrict__ b_ih, const float* __restrict__ b_hh,
    const float* __restrict__ a1w1, const float* __restrict__ a1b1,
    const float* __restrict__ a1w2, const float* __restrict__ a1b2,
    const float* __restrict__ g1_tab, const int* __restrict__ a2_tab,
    float* __restrict__ out) {
  __shared__ __align__(16) float ring[10][128];   // ring[s%10] = h_s
  __shared__ __align__(16) float hbuf[128];
  __shared__ __align__(16) float weighted[128];
  __shared__ __align__(16) float obs[128];
  __shared__ __align__(16) float z1[64];
  __shared__ __align__(16) float ghi[384];        // x@w_ih.T + b_ih
  __shared__ __align__(16) float ghh[384];        // weighted@w_hh.T + b_hh
  __shared__ __align__(16) float lastbuf[128];
  __shared__ __align__(16) float xcur[128];
  __shared__ float g1buf[10];
  __shared__ __align__(16) float w2buf[10][64];
  __shared__ __align__(16) float w1s[64][132];    // +4 pad keeps float4 align, 2-way banks
  __shared__ float bihs[384], bhhs[384], b1s[64], b2s[10];
  __shared__ int a2s;
  __shared__ int redi[8];
  __shared__ int last_s;

  const int tid = threadIdx.x;
  const int wave = tid >> 6, lane = tid & 63;
  const int b = blockIdx.x;

  // gemv mapping: quad = 4 k-chunks of 32; each thread owns 3 rows
  const int qk = lane & 3;
  const int mrow = (wave << 4) + (lane >> 2);     // 0..127
  const int r0 = 3 * mrow;                        // rows r0..r0+2 of 384

  // register-resident GRU weights (zero per-step streaming)
  float wih[96], whh[96];
  #pragma unroll
  for (int i = 0; i < 3; i++) {
    const float* wi = w_ih + (size_t)(r0 + i) * 128 + 32 * qk;
    const float* wh = w_hh + (size_t)(r0 + i) * 128 + 32 * qk;
    #pragma unroll
    for (int c = 0; c < 8; c++) {
      float4 vi = ((const float4*)wi)[c];
      float4 vh = ((const float4*)wh)[c];
      wih[i * 32 + 4 * c + 0] = vi.x; wih[i * 32 + 4 * c + 1] = vi.y;
      wih[i * 32 + 4 * c + 2] = vi.z; wih[i * 32 + 4 * c + 3] = vi.w;
      whh[i * 32 + 4 * c + 0] = vh.x; whh[i * 32 + 4 * c + 1] = vh.y;
      whh[i * 32 + 4 * c + 2] = vh.z; whh[i * 32 + 4 * c + 3] = vh.w;
    }
  }
  // init LDS
  for (int idx = tid; idx < 1280; idx += 512) ((float*)ring)[idx] = 0.f;
  if (tid < 128) weighted[tid] = 0.f;
  for (int idx = tid; idx < 8192; idx += 512) w1s[idx >> 7][idx & 127] = a1w1[idx];
  for (int idx = tid; idx < 640; idx += 512) w2buf[idx >> 6][idx & 63] = a1w2[idx];
  for (int idx = tid; idx < 384; idx += 512) { bihs[idx] = b_ih[idx]; bhhs[idx] = b_hh[idx]; }
  if (tid < 64) b1s[tid] = a1b1[tid];
  if (tid < 10) b2s[tid] = a1b2[tid];
  // mask reduction -> last index
  int mv = mask[(size_t)b * T_ + tid];
  #pragma unroll
  for (int off = 1; off < 64; off <<= 1) mv += __shfl_xor(mv, off);
  if (lane == 0) redi[wave] = mv;
  __syncthreads();
  if (tid == 0) {
    int s = 0;
    #pragma unroll
    for (int w = 0; w < 8; w++) s += redi[w];
    last_s = s - 1;
  }
  // initial prefetches
  float4 xreg = make_float4(0.f, 0.f, 0.f, 0.f);
  if (wave == 6 && lane < 32) {
    float4 v0 = ((const float4*)(x + (size_t)b * T_ * D_))[lane];
    *(float4*)&xcur[4 * lane] = v0;                     // x[b][0]
    xreg = ((const float4*)(x + ((size_t)b * T_ + 1) * D_))[lane];
  }
  float g1reg = 0.f;
  if (wave == 7 && lane < 10) g1reg = g1_tab[(size_t)b * 10 + lane];   // t=1 row
  int a2reg = 0;
  if (tid == 511) a2reg = a2_tab[b];                                    // t=1 row
  __syncthreads();
  const int last = last_s;

  // big gemv: ghi/ghh for all 384 rows from xcur and weighted
  auto do_gemv = [&]() {
    float ap0 = 0.f, ap1 = 0.f, ap2 = 0.f, aq0 = 0.f, aq1 = 0.f, aq2 = 0.f;
    const float4* xr = (const float4*)(xcur + 32 * qk);
    const float4* wr = (const float4*)(weighted + 32 * qk);
    #pragma unroll
    for (int c = 0; c < 8; c++) {
      float4 xv = xr[c], wv = wr[c];
      ap0 += wih[4*c+0]*xv.x + wih[4*c+1]*xv.y + wih[4*c+2]*xv.z + wih[4*c+3]*xv.w;
      aq0 += whh[4*c+0]*wv.x + whh[4*c+1]*wv.y + whh[4*c+2]*wv.z + whh[4*c+3]*wv.w;
      ap1 += wih[32+4*c+0]*xv.x + wih[32+4*c+1]*xv.y + wih[32+4*c+2]*xv.z + wih[32+4*c+3]*xv.w;
      aq1 += whh[32+4*c+0]*wv.x + whh[32+4*c+1]*wv.y + whh[32+4*c+2]*wv.z + whh[32+4*c+3]*wv.w;
      ap2 += wih[64+4*c+0]*xv.x + wih[64+4*c+1]*xv.y + wih[64+4*c+2]*xv.z + wih[64+4*c+3]*xv.w;
      aq2 += whh[64+4*c+0]*wv.x + whh[64+4*c+1]*wv.y + whh[64+4*c+2]*wv.z + whh[64+4*c+3]*wv.w;
    }
    ap0 += __shfl_xor(ap0, 1); ap0 += __shfl_xor(ap0, 2);
    ap1 += __shfl_xor(ap1, 1); ap1 += __shfl_xor(ap1, 2);
    ap2 += __shfl_xor(ap2, 1); ap2 += __shfl_xor(ap2, 2);
    aq0 += __shfl_xor(aq0, 1); aq0 += __shfl_xor(aq0, 2);
    aq1 += __shfl_xor(aq1, 1); aq1 += __shfl_xor(aq1, 2);
    aq2 += __shfl_xor(aq2, 1); aq2 += __shfl_xor(aq2, 2);
    if ((lane & 3) == 0) {
      ghi[r0+0] = ap0 + bihs[r0+0]; ghh[r0+0] = aq0 + bhhs[r0+0];
      ghi[r0+1] = ap1 + bihs[r0+1]; ghh[r0+1] = aq1 + bhhs[r0+1];
      ghi[r0+2] = ap2 + bihs[r0+2]; ghh[r0+2] = aq2 + bhhs[r0+2];
    }
  };
  // gates -> new h; push into ring + global
  auto do_gates = [&](int t) {
    if (tid < 128) {
      int j = tid;
      float ir = ghi[j],       hr = ghh[j];
      float iz = ghi[128 + j], hz = ghh[128 + j];
      float in_ = ghi[256 + j], hn = ghh[256 + j];
      float r  = 1.0f / (1.0f + expf(-(ir + hr)));
      float zz = 1.0f / (1.0f + expf(-(iz + hz)));
      float n  = tanhf(in_ + r * hn);
      float hw = weighted[j];
      float hnew = (1.0f - zz) * n + zz * hw;
      hbuf[j] = hnew;
      ring[t % 10][j] = hnew;
      out[(size_t)(B_ * H_) + ((size_t)b * T_ + t) * H_ + j] = hnew;
      if (t == last) lastbuf[j] = hnew;
    }
  };

  // ---- t = 0: h0 = gru(x0, 0) (weighted == 0) ----
  do_gemv();
  __syncthreads();
  do_gates(0);
  __syncthreads();

  // ---- t = 1..511 ----
  #pragma unroll 1
  for (int t = 1; t < T_; t++) {
    // prefetch-to-LDS + obs (disjoint thread groups)
    if (wave == 6 && lane < 32) {
      *(float4*)&xcur[4 * lane] = xreg;
      if (t < 511) xreg = ((const float4*)(x + ((size_t)b * T_ + t + 1) * D_))[lane];
    }
    if (wave == 7 && lane < 10) {
      g1buf[lane] = g1reg;
      if (t < 511) g1reg = g1_tab[((size_t)t * 256 + b) * 10 + lane];
    }
    if (tid == 511) {
      a2s = a2reg;
      if (t < 511) a2reg = a2_tab[(size_t)t * 256 + b];
    }
    if (tid < 128) {
      // obs = mean over buf slots a=0..9 (oldest..newest), matching np sequential order
      float s = 0.f;
      #pragma unroll
      for (int a = 0; a < 10; a++) s += ring[(t + a) % 10][tid];
      obs[tid] = s / 10.0f;
    }
    __syncthreads();
    // a1 hidden layer: z1 = tanh(obs @ w1.T + b1)
    {
      int mo = (wave << 3) + (lane >> 3), kc = lane & 7;
      const float4* op = (const float4*)(obs + 16 * kc);
      const float4* wp = (const float4*)(&w1s[mo][16 * kc]);
      float p = 0.f;
      #pragma unroll
      for (int c = 0; c < 4; c++) {
        float4 w4 = wp[c], o4 = op[c];
        p += w4.x * o4.x + w4.y * o4.y + w4.z * o4.z + w4.w * o4.w;
      }
      p += __shfl_xor(p, 1); p += __shfl_xor(p, 2); p += __shfl_xor(p, 4);
      if (kc == 0) z1[mo] = tanhf(p + b1s[mo]);
    }
    __syncthreads();
    // logits + sample a1 + weighted (wave 0 only)
    if (wave == 0) {
      int a = lane >> 2, kc = lane & 3;
      float p = 0.f;
      if (a < 10) {
        const float4* zp = (const float4*)(z1 + 16 * kc);
        const float4* wp = (const float4*)(&w2buf[a][16 * kc]);
        #pragma unroll
        for (int c = 0; c < 4; c++) {
          float4 zv = zp[c], w4 = wp[c];
          p += w4.x * zv.x + w4.y * zv.y + w4.z * zv.z + w4.w * zv.w;
        }
      }
      p += __shfl_xor(p, 1); p += __shfl_xor(p, 2);
      float val = -3.0e38f;
      if (a < 10) val = (p + b2s[a]) + g1buf[a];
      float best = 0.f; int bi = 0;
      #pragma unroll
      for (int aa = 0; aa < 10; aa++) {
        float v = __shfl(val, 4 * aa);
        if (aa == 0 || v > best) { best = v; bi = aa; }
      }
      int s1 = (t + bi) % 10;            // buf[a1] = h_{t-10+a1} = ring[(t+a1)%10]
      int s2 = (t + a2s) % 10;
      #pragma unroll
      for (int jj = lane; jj < 128; jj += 64) {
        float act = (ring[s1][jj] + ring[s2][jj]) * 0.5f;
        weighted[jj] = 0.5f * act + 0.5f * hbuf[jj];
      }
    }
    __syncthreads();
    do_gemv();
    __syncthreads();
    do_gates(t);
    __syncthreads();
  }
  if (tid < 128) out[(size_t)b * H_ + tid] = lastbuf[tid];
}

extern "C" void kernel_launch(void* const* d_in, const int* in_sizes, int n_in,
                              void* d_out, int out_size, void* d_ws, size_t ws_size,
                              hipStream_t stream) {
  (void)in_sizes; (void)n_in; (void)out_size; (void)ws_size;
  const float* x     = (const float*)d_in[0];
  const int*   mask  = (const int*)d_in[1];
  const float* w_ih  = (const float*)d_in[2];
  const float* w_hh  = (const float*)d_in[3];
  const float* b_ih  = (const float*)d_in[4];
  const float* b_hh  = (const float*)d_in[5];
  const float* a1w1  = (const float*)d_in[6];
  const float* a1b1  = (const float*)d_in[7];
  const float* a1w2  = (const float*)d_in[8];
  const float* a1b2  = (const float*)d_in[9];
  const float* a2w1  = (const float*)d_in[10];
  const float* a2b1  = (const float*)d_in[11];
  const float* a2w2  = (const float*)d_in[12];
  const float* a2b2  = (const float*)d_in[13];
  float* out = (float*)d_out;

  // workspace layout (~11 MB): g1 | g2 | keys(2048 u32) | a2 actions
  float*    g1       = (float*)d_ws;
  float*    g2       = g1 + NG;
  unsigned* keys_tab = (unsigned*)(g2 + NG);
  int*      a2_tab   = (int*)(keys_tab + 2048);

  p0_keys<<<4, 256, 0, stream>>>(keys_tab);
  p3_gumbel<<<10220, 256, 0, stream>>>(keys_tab, g1, g2);
  p2_a2<<<4088, 256, 0, stream>>>(x, a2w1, a2b1, a2w2, a2b2, g2, a2_tab);
  seq_kernel<<<256, 512, 0, stream>>>(x, mask, w_ih, w_hh, b_ih, b_hh,
                                      a1w1, a1b1, a1w2, a1b2, g1, a2_tab, out);
}